// Round 8
// baseline (474.554 us; speedup 1.0000x reference)
//
#include <hip/hip_runtime.h>
#include <cstdint>
#include <cstddef>

#define N_INST 200
#define HWPIX (448 * 448)        // 200704 pixels per mask
#define W64 3136                 // uint64 words per packed mask
#define W16 12544                // uint16 words per packed mask
#define SIGMA 2.0f
#define NCHUNK 6                 // K-split factor (phase 2)
#define NTILE 325                // triangular 8x8 tiles over 25x25 tile grid
#define NTASK (NTILE * NCHUNK)   // 1950 pair-wave tasks
#define NBLK 512                 // 512 blocks * 4 waves = 2048 waves >= NTASK
#define NTHREAD 256

// workspace layout (bytes)
#define P_SLAB  (N_INST * N_INST)
#define OFF_P   5017600                        // after packed (200*3136*8)
#define OFF_SP  (OFF_P + NCHUNK * P_SLAB * 4)  // 5,977,600
#define OFF_CMP (OFF_SP + NCHUNK * 256 * 4)    // 5,983,744
#define OFF_BAR (OFF_CMP + 1024)               // 5,984,768 (bar[0]=count, bar[1]=gen)

// ---------------------------------------------------------------------------
// Grid barrier for a NORMAL launch (round-7's hipLaunchCooperativeKernel was
// silently rejected -> out stayed zero). Correct by construction:
//  - all NBLK blocks co-resident: __launch_bounds__(256,2) caps VGPR<=256,
//    0 LDS -> >=2 blocks/CU -> 512 slots on an idle 256-CU device.
//  - __syncthreads() drains vmcnt(0) (all the block's stores reach L2);
//    __threadfence() on gfx950 = agent fence -> L2 writeback/invalidate
//    (cross-XCD safe, G16); count/gen are device-scope atomics (m20).
// Generation counter => reusable without re-init across the 3 uses.
// ---------------------------------------------------------------------------
__device__ __forceinline__ void grid_barrier(int* bar) {
    __syncthreads();
    if (threadIdx.x == 0) {
        __threadfence();   // release: flush this XCD's L2
        const int g = __hip_atomic_load(&bar[1], __ATOMIC_ACQUIRE,
                                        __HIP_MEMORY_SCOPE_AGENT);
        if (atomicAdd(&bar[0], 1) == NBLK - 1) {
            atomicExch(&bar[0], 0);
            __threadfence();
            atomicAdd(&bar[1], 1);
        } else {
            while (__hip_atomic_load(&bar[1], __ATOMIC_ACQUIRE,
                                     __HIP_MEMORY_SCOPE_AGENT) == g)
                __builtin_amdgcn_s_sleep(1);
        }
        __threadfence();   // acquire: invalidate this XCD's L2
    }
    __syncthreads();
}

__global__ void zero_bar_kernel(int* __restrict__ bar) {
    bar[0] = 0; bar[1] = 0;
}

// ---------------------------------------------------------------------------
// Fused 4-phase kernel (structure identical to round 7, which never ran):
//  P1 bitpack (coalesced 16B/lane; fixed pixel permutation — exact for AND/
//     popcount), P2 8x8-tile popcount(AND) K-split 6 with ulonglong2 loads,
//  P3 IoU + column max (comp) with d kept in registers, P4 min+exp epilogue.
// ---------------------------------------------------------------------------
__global__ void __launch_bounds__(NTHREAD, 2)
fused_kernel(const float* __restrict__ seg,
             const float* __restrict__ scores,
             const int* __restrict__ labels,
             float* __restrict__ out,
             uint64_t* __restrict__ packed,
             int* __restrict__ P,
             int* __restrict__ SP,
             float* __restrict__ comp,
             int* __restrict__ bar) {
    const int tid  = blockIdx.x * NTHREAD + threadIdx.x;
    const int wv   = tid >> 6;          // global wave id, 0..2047
    const int lane = tid & 63;

    // ---- Phase 1: bitpack -------------------------------------------------
    // word w = mask*W16 + bx*256 + t holds bit 4s+q <- pixel
    // mask*HWPIX + bx*4096 + s*1024 + t*4 + q. Lane-contiguous float4 loads.
    {
        uint16_t* packed16 = (uint16_t*)packed;
        for (int w = tid; w < N_INST * W16; w += NBLK * NTHREAD) {
            const int mask = w / W16;
            const int widx = w - mask * W16;
            const int bx = widx >> 8, t = widx & 255;
            const float4* s4 = (const float4*)(seg + (size_t)mask * HWPIX
                                                   + (size_t)bx * 4096);
            uint32_t m = 0;
#pragma unroll
            for (int s = 0; s < 4; ++s) {
                const float4 v = s4[s * 256 + t];
                uint32_t b = 0;
                b |= (v.x > 0.5f) ? 1u : 0u;
                b |= (v.y > 0.5f) ? 2u : 0u;
                b |= (v.z > 0.5f) ? 4u : 0u;
                b |= (v.w > 0.5f) ? 8u : 0u;
                m |= b << (4 * s);
            }
            packed16[w] = (uint16_t)m;
        }
    }
    grid_barrier(bar);

    // ---- Phase 2: pairwise intersection counts ----------------------------
    // task wt -> (tile, chunk). 24 ulonglong2 pair-blocks of 128 words: 4 per
    // chunk; chunk 5 also owns the 64-word tail. Bits/lane <= 576 ->
    // wave-sum <= 36864 < 2^16 -> counts packed 2-per-int (exact butterfly).
    if (wv < NTASK) {
        const int t     = wv / NCHUNK;
        const int chunk = wv - t * NCHUNK;
        int jt = (int)((sqrtf((float)(8 * t + 1)) - 1.0f) * 0.5f);
        while ((jt + 1) * (jt + 2) / 2 <= t) ++jt;
        while (jt * (jt + 1) / 2 > t) --jt;
        const int it = t - jt * (jt + 1) / 2;
        const int i0 = 8 * it, j0 = 8 * jt;

        const uint64_t* A = packed + (size_t)i0 * W64;
        const uint64_t* B = packed + (size_t)j0 * W64;

        int c[64];
#pragma unroll
        for (int x = 0; x < 64; ++x) c[x] = 0;

        for (int pb = chunk * 4; pb < chunk * 4 + 4; ++pb) {
            const int k2 = pb * 128 + lane * 2;
            ulonglong2 a[8], b[8];
#pragma unroll
            for (int r = 0; r < 8; ++r) {
                a[r] = *(const ulonglong2*)(A + (size_t)r * W64 + k2);
                b[r] = *(const ulonglong2*)(B + (size_t)r * W64 + k2);
            }
#pragma unroll
            for (int r = 0; r < 8; ++r)
#pragma unroll
                for (int cc = 0; cc < 8; ++cc)
                    c[r * 8 + cc] += __popcll(a[r].x & b[cc].x)
                                   + __popcll(a[r].y & b[cc].y);
        }
        if (chunk == 5) {                           // words 3072..3135
            const int k = 3072 + lane;
            uint64_t a[8], b[8];
#pragma unroll
            for (int r = 0; r < 8; ++r) {
                a[r] = A[(size_t)r * W64 + k];
                b[r] = B[(size_t)r * W64 + k];
            }
#pragma unroll
            for (int r = 0; r < 8; ++r)
#pragma unroll
                for (int cc = 0; cc < 8; ++cc)
                    c[r * 8 + cc] += __popcll(a[r] & b[cc]);
        }

        int p[32];
#pragma unroll
        for (int m = 0; m < 32; ++m) p[m] = c[2 * m] + (c[2 * m + 1] << 16);
#pragma unroll
        for (int off = 1; off < 64; off <<= 1) {
#pragma unroll
            for (int m = 0; m < 32; ++m) p[m] += __shfl_xor(p[m], off, 64);
        }

        if (lane == 0) {
#pragma unroll
            for (int r = 0; r < 8; ++r) {
#pragma unroll
                for (int cc = 0; cc < 8; ++cc) {
                    const int idx = r * 8 + cc;
                    const int val = (idx & 1) ? (int)(((unsigned)p[idx >> 1]) >> 16)
                                              : (p[idx >> 1] & 0xFFFF);
                    const int i = i0 + r, j = j0 + cc;
                    if (i < j)       P[chunk * P_SLAB + j * N_INST + i] = val;
                    else if (i == j) SP[chunk * 256 + i] = val;  // |mask_i|
                }
            }
        }
    }
    grid_barrier(bar);

    // ---- Phase 3: IoU column j + comp[j] = max_{i<j} decay_iou[i][j] ------
    float d[4] = {0.0f, 0.0f, 0.0f, 0.0f};
    const int j = wv;
    if (j < N_INST) {
        int sj = 0;
#pragma unroll
        for (int cch = 0; cch < NCHUNK; ++cch) sj += SP[cch * 256 + j];
        const int lj = labels[j];
        float m = 0.0f;
#pragma unroll
        for (int q = 0; q < 4; ++q) {
            const int i = lane + 64 * q;
            if (i < j) {
                int inter = 0;
#pragma unroll
                for (int cch = 0; cch < NCHUNK; ++cch)
                    inter += P[cch * P_SLAB + j * N_INST + i];
                int si = 0;
#pragma unroll
                for (int cch = 0; cch < NCHUNK; ++cch) si += SP[cch * 256 + i];
                const float iou = (float)inter / (float)(si + sj - inter);
                d[q] = (labels[i] == lj) ? iou : 0.0f;
                m = fmaxf(m, d[q]);
            }
        }
#pragma unroll
        for (int off = 1; off < 64; off <<= 1)
            m = fmaxf(m, __shfl_xor(m, off, 64));
        if (lane == 0) comp[j] = m;
    }
    grid_barrier(bar);

    // ---- Phase 4: out[j] = scores[j]*exp(SIGMA*min_i(comp_i^2 - d_ij^2)) --
    // (min of exp == exp of min; d[q]=0 for i>=j or label mismatch.)
    if (j < N_INST) {
        float mn = 3.4e38f;
#pragma unroll
        for (int q = 0; q < 4; ++q) {
            const int i = lane + 64 * q;
            if (i < N_INST) {
                const float ci = comp[i];
                mn = fminf(mn, ci * ci - d[q] * d[q]);
            }
        }
#pragma unroll
        for (int off = 1; off < 64; off <<= 1)
            mn = fminf(mn, __shfl_xor(mn, off, 64));
        if (lane == 0) out[j] = scores[j] * expf(SIGMA * mn);
    }
}

extern "C" void kernel_launch(void* const* d_in, const int* in_sizes, int n_in,
                              void* d_out, int out_size, void* d_ws, size_t ws_size,
                              hipStream_t stream) {
    const float* seg    = (const float*)d_in[0];   // (200,448,448) fp32 binary
    const float* scores = (const float*)d_in[1];   // (200,) fp32
    const int*   labels = (const int*)d_in[2];     // (200,) int32
    float* out = (float*)d_out;                    // (200,) fp32

    uint64_t* packed = (uint64_t*)d_ws;
    int*      P      = (int*)((char*)d_ws + OFF_P);
    int*      SP     = (int*)((char*)d_ws + OFF_SP);
    float*    comp   = (float*)((char*)d_ws + OFF_CMP);
    int*      bar    = (int*)((char*)d_ws + OFF_BAR);

    zero_bar_kernel<<<1, 1, 0, stream>>>(bar);
    fused_kernel<<<NBLK, NTHREAD, 0, stream>>>(seg, scores, labels, out,
                                               packed, P, SP, comp, bar);
}

// Round 9
// 250.082 us; speedup vs baseline: 1.8976x; 1.8976x over previous
//
#include <hip/hip_runtime.h>
#include <cstdint>
#include <cstddef>

#define N_INST 200
#define HWPIX (448 * 448)        // 200704 pixels per mask
#define W64 3136                 // uint64 words per packed mask
#define SIGMA 2.0f
#define NCHUNK 8                 // K-split factor in pair kernel
#define NTILE 325                // triangular 8x8 tiles over a 25x25 tile grid

// workspace layout (bytes)
#define P_SLAB  (N_INST * N_INST)              // ints per partial-count slab
#define OFF_P   5017600                        // after packed (200*3136*8)
#define OFF_SP  (OFF_P + NCHUNK * P_SLAB * 4)  // per-chunk per-mask popcounts
#define OFF_CMP (OFF_SP + NCHUNK * 256 * 4)    // comp[200] fp32

// ---------------------------------------------------------------------------
// K1: bitpack with MLP=16. grid (49, 200), 64-thread (1-wave) blocks; thread t
// issues 16 INDEPENDENT lane-contiguous float4 loads (1 KB/wave/instruction)
// and stores one uint64 word. R1 evidence: pack at MLP=1 was latency-bound
// (909 GB/s); R2-R6 ran MLP=4. 16 in-flight loads/thread is the fix.
// Fixed pixel permutation (exact for AND/popcount):
//   word w = bx*64 + t, bit 4s+q  <-  pixel bx*4096 + s*256 + t*4 + q.
// ---------------------------------------------------------------------------
__global__ void __launch_bounds__(64)
pack_kernel(const float* __restrict__ seg, uint64_t* __restrict__ packed) {
    const int t = threadIdx.x;                 // 0..63
    const float4* s4 = (const float4*)(seg + (size_t)blockIdx.y * HWPIX
                                           + (size_t)blockIdx.x * 4096);
    float4 v[16];
#pragma unroll
    for (int s = 0; s < 16; ++s) v[s] = s4[s * 64 + t];   // 16 loads in flight
    uint64_t m = 0;
#pragma unroll
    for (int s = 0; s < 16; ++s) {
        uint32_t b = 0;
        b |= (v[s].x > 0.5f) ? 1u : 0u;
        b |= (v[s].y > 0.5f) ? 2u : 0u;
        b |= (v[s].z > 0.5f) ? 4u : 0u;
        b |= (v[s].w > 0.5f) ? 8u : 0u;
        m |= (uint64_t)b << (4 * s);
    }
    packed[(size_t)blockIdx.y * W64 + blockIdx.x * 64 + t] = m;
}

// ---------------------------------------------------------------------------
// K2: pairwise intersection counts, 8x8 tile per wave, K-split by NCHUNK=8.
// 325 tiles x 8 chunks = 2600 waves. Off-diagonal -> P[chunk][j][i];
// diagonal (i==j) -> SP[chunk][i] (per-mask popcounts for free, no atomics).
// Wave-sums <= 7 iters * 64 bits * 64 lanes = 28672 < 2^16: counts packed
// 2-per-int -> 32-reg x 6-step butterfly (exact mod 2^32).
// (R5 config — measured best; R6's K-split 16 was neutral.)
// ---------------------------------------------------------------------------
__global__ void pair_kernel(const uint64_t* __restrict__ packed,
                            int* __restrict__ P,
                            int* __restrict__ SP) {
    const int wt   = blockIdx.x * 4 + (threadIdx.x >> 6);   // 0..2599
    const int lane = threadIdx.x & 63;
    const int t     = wt >> 3;        // tile id 0..324
    const int chunk = wt & 7;

    // decode triangular tile id: t = jt*(jt+1)/2 + it, 0 <= it <= jt <= 24
    int jt = (int)((sqrtf((float)(8 * t + 1)) - 1.0f) * 0.5f);
    while ((jt + 1) * (jt + 2) / 2 <= t) ++jt;
    while (jt * (jt + 1) / 2 > t) --jt;
    const int it = t - jt * (jt + 1) / 2;
    const int i0 = 8 * it, j0 = 8 * jt;

    const int ks = (chunk * 49) >> 3;          // 0,6,12,18,24,30,36,42
    const int ke = ((chunk + 1) * 49) >> 3;    // 6,...,42,49

    const uint64_t* A = packed + (size_t)i0 * W64;
    const uint64_t* B = packed + (size_t)j0 * W64;

    int c[64];
#pragma unroll
    for (int x = 0; x < 64; ++x) c[x] = 0;

    for (int kb = ks; kb < ke; ++kb) {
        const int k = kb * 64 + lane;
        uint64_t a[8], b[8];
#pragma unroll
        for (int r = 0; r < 8; ++r) { a[r] = A[k + r * W64]; b[r] = B[k + r * W64]; }
#pragma unroll
        for (int r = 0; r < 8; ++r)
#pragma unroll
            for (int cc = 0; cc < 8; ++cc)
                c[r * 8 + cc] += __popcll(a[r] & b[cc]);
    }

    int p[32];
#pragma unroll
    for (int m = 0; m < 32; ++m) p[m] = c[2 * m] + (c[2 * m + 1] << 16);
#pragma unroll
    for (int off = 1; off < 64; off <<= 1) {
#pragma unroll
        for (int m = 0; m < 32; ++m) p[m] += __shfl_xor(p[m], off, 64);
    }

    if (lane == 0) {
#pragma unroll
        for (int r = 0; r < 8; ++r) {
#pragma unroll
            for (int cc = 0; cc < 8; ++cc) {
                const int idx = r * 8 + cc;
                const int val = (idx & 1) ? (int)(((unsigned)p[idx >> 1]) >> 16)
                                          : (p[idx >> 1] & 0xFFFF);
                const int i = i0 + r, j = j0 + cc;
                if (i < j)       P[chunk * P_SLAB + j * N_INST + i] = val;
                else if (i == j) SP[chunk * 256 + i] = val;   // popc(a&a)=|mask|
            }
        }
    }
}

// ---------------------------------------------------------------------------
// K3: reduce chunk partials -> decay_iou[i][j] (i<j) for column j, fused with
// comp[j] = max_{i<j} decay_iou[i][j]. Block j keeps its column in d[]
// nowhere — writes DTf row for K4 AND reduces the max in the same pass.
// ---------------------------------------------------------------------------
#define OFF_DT  (OFF_CMP + 1024)               // DTf[j*200+i] fp32, i<j only

__global__ void iou_comp_kernel(const int* __restrict__ P,
                                const int* __restrict__ SP,
                                const int* __restrict__ labels,
                                float* __restrict__ DTf,
                                float* __restrict__ comp) {
    const int j = blockIdx.x;
    const int t = threadIdx.x;
    int sj = 0;
#pragma unroll
    for (int cch = 0; cch < NCHUNK; ++cch) sj += SP[cch * 256 + j];
    const int lj = labels[j];
    float m = 0.0f;                            // j=0: empty column -> comp 0
    for (int i = t; i < j; i += 64) {
        int inter = 0;
#pragma unroll
        for (int cch = 0; cch < NCHUNK; ++cch)
            inter += P[cch * P_SLAB + j * N_INST + i];
        int si = 0;
#pragma unroll
        for (int cch = 0; cch < NCHUNK; ++cch) si += SP[cch * 256 + i];
        const float iou = (float)inter / (float)(si + sj - inter);
        const float d = (labels[i] == lj) ? iou : 0.0f;
        DTf[j * N_INST + i] = d;
        m = fmaxf(m, d);
    }
#pragma unroll
    for (int off = 1; off < 64; off <<= 1) m = fmaxf(m, __shfl_xor(m, off, 64));
    if (t == 0) comp[j] = m;
}

// ---------------------------------------------------------------------------
// K4: out[j] = scores[j] * exp(SIGMA * min_i(comp[i]^2 - d_ij^2)),
//     d_ij = decay_iou[i][j] = (i<j ? DTf[j*200+i] : 0).
// (min of exp == exp of min; exp monotone.) Coalesced row reads, L2-hot.
// ---------------------------------------------------------------------------
__global__ void finalize_kernel(const float* __restrict__ DTf,
                                const float* __restrict__ comp,
                                const float* __restrict__ scores,
                                float* __restrict__ out) {
    const int j = blockIdx.x;
    const int t = threadIdx.x;
    const float* row = DTf + (size_t)j * N_INST;
    float mn = 3.4e38f;
    for (int i = t; i < N_INST; i += 64) {
        const float ci = comp[i];
        float v = ci * ci;
        if (i < j) { const float d = row[i]; v -= d * d; }
        mn = fminf(mn, v);
    }
#pragma unroll
    for (int off = 1; off < 64; off <<= 1) mn = fminf(mn, __shfl_xor(mn, off, 64));
    if (t == 0) out[j] = scores[j] * expf(SIGMA * mn);
}

extern "C" void kernel_launch(void* const* d_in, const int* in_sizes, int n_in,
                              void* d_out, int out_size, void* d_ws, size_t ws_size,
                              hipStream_t stream) {
    const float* seg    = (const float*)d_in[0];   // (200,448,448) fp32 binary
    const float* scores = (const float*)d_in[1];   // (200,) fp32
    const int*   labels = (const int*)d_in[2];     // (200,) int32
    float* out = (float*)d_out;                    // (200,) fp32

    uint64_t* packed = (uint64_t*)d_ws;
    int*      P      = (int*)((char*)d_ws + OFF_P);
    int*      SP     = (int*)((char*)d_ws + OFF_SP);
    float*    comp   = (float*)((char*)d_ws + OFF_CMP);
    float*    DTf    = (float*)((char*)d_ws + OFF_DT);

    {
        dim3 grid(49, N_INST);
        pack_kernel<<<grid, 64, 0, stream>>>(seg, packed);
    }
    pair_kernel<<<NTILE * NCHUNK / 4, 256, 0, stream>>>(packed, P, SP);
    iou_comp_kernel<<<N_INST, 64, 0, stream>>>(P, SP, labels, DTf, comp);
    finalize_kernel<<<N_INST, 64, 0, stream>>>(DTf, comp, scores, out);
}